// Round 1
// 458.625 us; speedup vs baseline: 1.0007x; 1.0007x over previous
//
#include <hip/hip_runtime.h>

// ---------------------------------------------------------------------------
// Attention_16698832847178: B=2,S=2048,D=2048,H=16,HD=128,L=10
// R6: gemm_qkv rewritten as 256x256-tile 8-phase pipelined GEMM (HK-style
// schedule: counted vmcnt(6), raw s_barrier pairs, setprio around MFMA,
// XOR-swizzled LDS, bijective XCD swizzle). RoPE + per-wave V-transpose
// epilogues re-derived for the 8-wave (2Mx4N) fragment layout.
// wo-GEMM stays on the 128^2 kernel (256^2 would leave half the CUs idle).
// ---------------------------------------------------------------------------

typedef unsigned short ushort_t;
typedef unsigned int uint32;
typedef __attribute__((ext_vector_type(8))) short bf16x8;   // 8 bf16 = 4 VGPRs
typedef __attribute__((ext_vector_type(4))) float f32x4;

__device__ __forceinline__ void async16(void* lds, const void* g) {
  __builtin_amdgcn_global_load_lds((const __attribute__((address_space(1))) void*)g,
                                   (__attribute__((address_space(3))) void*)lds,
                                   16, 0, 0);
}
__device__ __forceinline__ ushort_t f2bf(float f) {
  uint32 u = __float_as_uint(f);
  u += 0x7FFFu + ((u >> 16) & 1u);   // round-to-nearest-even
  return (ushort_t)(u >> 16);
}
__device__ __forceinline__ float bf2f(ushort_t b) {
  return __uint_as_float(((uint32)b) << 16);
}
// value from lane^1 via DPP quad_perm [1,0,3,2] (VALU, no LDS)
__device__ __forceinline__ float dpp_xor1(float v) {
  return __int_as_float(__builtin_amdgcn_update_dpp(
      0, __float_as_int(v), 0xB1, 0xf, 0xf, true));
}
#define DPP_MAX(t, ctrl) \
  t = fmaxf(t, __int_as_float(__builtin_amdgcn_update_dpp( \
      0, __float_as_int(t), (ctrl), 0xf, 0xf, true)))
#define DPP_ADD(t, ctrl) \
  t += __int_as_float(__builtin_amdgcn_update_dpp( \
      0, __float_as_int(t), (ctrl), 0xf, 0xf, true))
__device__ __forceinline__ float rowmax16(float t) {
  DPP_MAX(t, 0xB1);   // xor 1
  DPP_MAX(t, 0x4E);   // xor 2
  t = fmaxf(t, __int_as_float(__builtin_amdgcn_ds_swizzle(
      __float_as_int(t), 0x101F)));                  // xor 4
  DPP_MAX(t, 0x128);  // row_ror:8 -> xor 8 (halves uniform after xor1/2/4)
  return t;
}
__device__ __forceinline__ float rowsum16(float t) {
  DPP_ADD(t, 0xB1);
  DPP_ADD(t, 0x4E);
  t += __int_as_float(__builtin_amdgcn_ds_swizzle(__float_as_int(t), 0x101F));
  DPP_ADD(t, 0x128);
  return t;
}

// ---------------------------------------------------------------------------
// cast x (fp32) -> bf16, 8 elements/thread
__global__ __launch_bounds__(256) void cast_x_kernel(const float* __restrict__ x,
                                                     ushort_t* __restrict__ Xb) {
  size_t i = ((size_t)blockIdx.x * 256 + threadIdx.x) * 8;
  float4 a = *(const float4*)(x + i);
  float4 b = *(const float4*)(x + i + 4);
  uint4 o;
  o.x = (uint32)f2bf(a.x) | ((uint32)f2bf(a.y) << 16);
  o.y = (uint32)f2bf(a.z) | ((uint32)f2bf(a.w) << 16);
  o.z = (uint32)f2bf(b.x) | ((uint32)f2bf(b.y) << 16);
  o.w = (uint32)f2bf(b.z) | ((uint32)f2bf(b.w) << 16);
  *(uint4*)(Xb + i) = o;
}

// ---------------------------------------------------------------------------
// pack rope table: fcs[s][fi] = (cos, sin)
__global__ __launch_bounds__(256) void rope_pack_kernel(
    const float* __restrict__ fc, const float* __restrict__ fs,
    float2* __restrict__ fcs) {
  int i = blockIdx.x * 256 + threadIdx.x;   // < 131072
  fcs[i] = make_float2(fc[i], fs[i]);
}

// ---------------------------------------------------------------------------
// W[k][n] fp32 -> Wt[n][k] bf16 (64x64 tiles), dword stores
__global__ __launch_bounds__(256) void transpose_w_kernel(
    const float* __restrict__ w0, const float* __restrict__ w1,
    const float* __restrict__ w2, const float* __restrict__ w3,
    ushort_t* __restrict__ outBase) {
  const float* W = (blockIdx.z == 0) ? w0 : (blockIdx.z == 1) ? w1
                 : (blockIdx.z == 2) ? w2 : w3;
  ushort_t* Wt = outBase + (size_t)blockIdx.z * 4194304;  // 2048*2048
  __shared__ float L[64][65];
  int t = threadIdx.x, tc = t & 63, tr = t >> 6;
  int k0 = blockIdx.x * 64, n0 = blockIdx.y * 64;
  for (int i = 0; i < 16; ++i) {
    int r = i * 4 + tr;
    L[r][tc] = W[(size_t)(k0 + r) * 2048 + n0 + tc];
  }
  __syncthreads();
  int tr8 = t >> 5, tc2 = t & 31;
  for (int i = 0; i < 8; ++i) {
    int r = i * 8 + tr8;
    uint32 pk = (uint32)f2bf(L[2 * tc2][r]) | ((uint32)f2bf(L[2 * tc2 + 1][r]) << 16);
    *(uint32*)(Wt + (size_t)(n0 + r) * 2048 + k0 + 2 * tc2) = pk;
  }
}

// ---------------------------------------------------------------------------
// adapter projections: ak/av[l][n] = sum_k adapter[l][k] * W[k][n]  (fp32)
__global__ __launch_bounds__(256) void adapter_kv_kernel(
    const float* __restrict__ adapter, const float* __restrict__ wk,
    const float* __restrict__ wv, float* __restrict__ ak, float* __restrict__ av) {
  const float* W = blockIdx.z ? wv : wk;
  float* out = blockIdx.z ? av : ak;
  __shared__ float As[10][128];
  int t = threadIdx.x;
  int k0 = blockIdx.y * 128;
  for (int i = t; i < 1280; i += 256)
    As[i >> 7][i & 127] = adapter[(size_t)(i >> 7) * 2048 + k0 + (i & 127)];
  __syncthreads();
  int n = blockIdx.x * 256 + t;
  float acc[10];
#pragma unroll
  for (int l = 0; l < 10; ++l) acc[l] = 0.f;
  for (int kk = 0; kk < 128; ++kk) {
    float wv_ = W[(size_t)(k0 + kk) * 2048 + n];
#pragma unroll
    for (int l = 0; l < 10; ++l) acc[l] += As[l][kk] * wv_;
  }
#pragma unroll
  for (int l = 0; l < 10; ++l) atomicAdd(&out[l * 2048 + n], acc[l]);
}

// ---------------------------------------------------------------------------
// pack ak/av (fp32) into MFMA-fragment-friendly bf16 buffers:
// akb[h][l(16)][d(128)] (l>=10 zero), avb[h][d(128)][l(32)] (l>=10 zero)
__global__ __launch_bounds__(256) void adapter_pack_kernel(
    const float* __restrict__ ak, const float* __restrict__ av,
    ushort_t* __restrict__ akb, ushort_t* __restrict__ avb) {
  int t = blockIdx.x * 256 + threadIdx.x;   // 65536 threads
  if (t < 32768) {
    int h = t >> 11, l = (t >> 7) & 15, d = t & 127;
    akb[t] = (l < 10) ? f2bf(ak[l * 2048 + h * 128 + d]) : (ushort_t)0;
  }
  int h = t >> 12, d = (t >> 5) & 127, l = t & 31;
  avb[t] = (l < 10) ? f2bf(av[l * 2048 + h * 128 + d]) : (ushort_t)0;
}

// ---------------------------------------------------------------------------
// Fused QKV GEMM, 256x256 tile, 8-phase pipelined schedule.
// C[4096, 6144] = Xb[4096,2048] x WtQKV[6144,2048]^T.
// 8 waves (2M x 4N), per-wave C = 128x64. BK=64, double-buffered 128KB LDS.
// Per K-tile: 4 phases {ds_read subtile | stage 1 half-slot | bar | lgkm0 |
// setprio(1) 16xMFMA setprio(0) | bar}; counted vmcnt(6) once per tile.
// Staging runs 7 half-slots ahead; restage into the live buffer only targets
// retired regions (B fully read at phase0; A strips retire per phase).
// Q,K segments: RoPE fused. V segment: per-wave 64x128 LDS transpose -> Vt.
// ---------------------------------------------------------------------------
#define BARX() asm volatile("s_barrier" ::: "memory")
#define LGKM0() asm volatile("s_waitcnt lgkmcnt(0)" ::: "memory")
#define VMCNT6() asm volatile("s_waitcnt vmcnt(6)" ::: "memory")
#define VMCNT0() asm volatile("s_waitcnt vmcnt(0)" ::: "memory")

__global__ __launch_bounds__(512, 2) void gemm_qkv256_kernel(
    const ushort_t* __restrict__ A, const ushort_t* __restrict__ Bt,
    ushort_t* __restrict__ outQ, ushort_t* __restrict__ outK,
    ushort_t* __restrict__ Vt, const float2* __restrict__ fcs) {
  __shared__ char lds[131072];
  const int tid = threadIdx.x;
  const int w = tid >> 6, lane = tid & 63, quad = lane >> 4, l15 = lane & 15;
  const int wr = w >> 2, wc = w & 3;
  const int nt = 32;   // K/64

  // bijective XCD swizzle: 384 wgs = 8 XCDs x 48; each XCD gets 3 contiguous
  // B-panels (3MB, L2-resident) x all 16 M-tiles.
  const int wg = (blockIdx.x & 7) * 48 + (blockIdx.x >> 3);
  const size_t bm0 = (size_t)(wg & 15) * 256;
  const size_t bn0 = (size_t)(wg >> 4) * 256;

  char* const pA0 = lds;
  char* const pA1 = lds + 32768;
  char* const pB0 = lds + 65536;
  char* const pB1 = lds + 98304;

#define PAT(T) ((((T) & 1) ? pA1 : pA0))
#define PBT(T) ((((T) & 1) ? pB1 : pB0))
// stage one 64-row segment: 8 rows/wave, 1x async16/thread. LDS written
// linearly (lane*16 = (lane>>3)*128 + (lane&7)*16); swizzle applied on the
// GLOBAL source chunk so reads use chunk ^ (row&7).
#define SEG16(OP, LDSB, GROW, T)                                               \
  do {                                                                         \
    int rr_ = w * 8 + (lane >> 3);                                             \
    int cl_ = (lane & 7) ^ (rr_ & 7);                                          \
    async16((LDSB) + w * 1024,                                                 \
            (OP) + ((GROW) + (size_t)rr_) * 2048 + (size_t)((T) * 64 + cl_ * 8)); \
  } while (0)
#define ST_A01(T)                                                   \
  do { if ((T) < nt) { SEG16(A, PAT(T), bm0, (T));                  \
                       SEG16(A, PAT(T) + 16384, bm0 + 128, (T)); } } while (0)
#define ST_A23(T)                                                   \
  do { if ((T) < nt) { SEG16(A, PAT(T) + 8192, bm0 + 64, (T));      \
                       SEG16(A, PAT(T) + 24576, bm0 + 192, (T)); } } while (0)
#define ST_B01(T)                                                   \
  do { if ((T) < nt) { SEG16(Bt, PBT(T), bn0, (T));                 \
                       SEG16(Bt, PBT(T) + 8192, bn0 + 64, (T)); } } while (0)
#define ST_B23(T)                                                   \
  do { if ((T) < nt) { SEG16(Bt, PBT(T) + 16384, bn0 + 128, (T));   \
                       SEG16(Bt, PBT(T) + 24576, bn0 + 192, (T)); } } while (0)

  f32x4 acc[8][4];
  f32x4 z4 = {0.f, 0.f, 0.f, 0.f};
#pragma unroll
  for (int i = 0; i < 8; ++i)
#pragma unroll
    for (int j = 0; j < 4; ++j) acc[i][j] = z4;

  // prologue: 7 staging slots (tile0 complete + 3 slots of tile1 in flight)
  ST_A01(0); ST_A23(0); ST_B01(0); ST_B23(0);
  ST_B01(1); ST_B23(1); ST_A01(1);
  VMCNT6();
  BARX();

// one phase: read 2 A-frags (both k-halves), issue one stage slot, barrier,
// wait LDS, prio-boosted 16 MFMA, barrier.
#define APHASE(PI, STAGE_STMT, TAIL_STMT)                                      \
  do {                                                                         \
    bf16x8 af[2][2];                                                           \
    _Pragma("unroll") for (int ii = 0; ii < 2; ++ii) {                         \
      int arow = wr * 128 + ((PI) * 2 + ii) * 16 + l15;                        \
      _Pragma("unroll") for (int ks = 0; ks < 2; ++ks)                         \
        af[ii][ks] = *(const bf16x8*)(pA + arow * 128 +                        \
                                      (((ks * 4 + quad) ^ (arow & 7)) * 16));  \
    }                                                                          \
    STAGE_STMT;                                                                \
    BARX();                                                                    \
    LGKM0();                                                                   \
    __builtin_amdgcn_s_setprio(1);                                             \
    _Pragma("unroll") for (int ks = 0; ks < 2; ++ks)                           \
      _Pragma("unroll") for (int ii = 0; ii < 2; ++ii)                         \
        _Pragma("unroll") for (int j = 0; j < 4; ++j)                          \
          acc[(PI) * 2 + ii][j] = __builtin_amdgcn_mfma_f32_16x16x32_bf16(     \
              af[ii][ks], bf[j][ks], acc[(PI) * 2 + ii][j], 0, 0, 0);          \
    __builtin_amdgcn_s_setprio(0);                                             \
    TAIL_STMT;                                                                 \
    BARX();                                                                    \
  } while (0)

#pragma unroll 2
  for (int t = 0; t < nt; ++t) {
    const char* pA = PAT(t);
    const char* pB = PBT(t);
    bf16x8 bf[4][2];   // whole wave B-slice in registers (retires B at p0)
#pragma unroll
    for (int j = 0; j < 4; ++j) {
      int brow = wc * 64 + j * 16 + l15;
#pragma unroll
      for (int ks = 0; ks < 2; ++ks)
        bf[j][ks] = *(const bf16x8*)(pB + brow * 128 +
                                     (((ks * 4 + quad) ^ (brow & 7)) * 16));
    }
    APHASE(0, ST_A23(t + 1), (void)0);
    APHASE(1, ST_B01(t + 2), (void)0);
    APHASE(2, ST_B23(t + 2), (void)0);
    APHASE(3, ST_A01(t + 2), { if (t == nt - 2) VMCNT0(); else VMCNT6(); });
  }

  // ---------------- epilogue ----------------
  const int seg = (int)(bn0 >> 11);   // 0=Q, 1=K, 2=V (256 divides 2048)
  if (seg < 2) {
    ushort_t* ob = seg ? outK : outQ;
#pragma unroll
    for (int i = 0; i < 8; ++i)
#pragma unroll
      for (int r = 0; r < 4; ++r) {
        size_t m = bm0 + wr * 128 + i * 16 + quad * 4 + r;
        int s = (int)(m & 2047);
#pragma unroll
        for (int j = 0; j < 4; ++j) {
          size_t ngl = bn0 + wc * 64 + j * 16 + l15;
          size_t n = ngl & 2047;
          float v = acc[i][j][r];
          float v2 = dpp_xor1(v);             // RoPE pair partner (col n^1)
          int fi = ((int)n & 127) >> 1;
          float2 cs = fcs[s * 64 + fi];
          v = (lane & 1) ? (v2 * cs.y + v * cs.x) : (v * cs.x - v2 * cs.y);
          ob[m * 2048 + n] = f2bf(v);
        }
      }
  } else {
    // V segment: per-wave 64(n) x 128(m) transpose patch through LDS
    // (main LDS reused after the final barrier; per-wave private -> no bar).
    // qword q0 holds m-locals 4q0..4q0+3; slot XOR-swizzled by row.
    char* T = lds + w * 16384;
#pragma unroll
    for (int i = 0; i < 8; ++i)
#pragma unroll
      for (int j = 0; j < 4; ++j) {
        int nn = j * 16 + l15;
        int q0 = i * 4 + quad;
        int slot = q0 ^ (nn & 31);
        uint32 p01 = (uint32)f2bf(acc[i][j][0]) | ((uint32)f2bf(acc[i][j][1]) << 16);
        uint32 p23 = (uint32)f2bf(acc[i][j][2]) | ((uint32)f2bf(acc[i][j][3]) << 16);
        *(uint32*)(T + nn * 256 + slot * 8) = p01;
        *(uint32*)(T + nn * 256 + slot * 8 + 4) = p23;
      }
    const int n2b = (int)(bn0 & 2047) + wc * 64;
    const int h = n2b >> 7;
    const size_t d0 = (size_t)(n2b & 127);
    const int b = (int)(bm0 >> 11);
    const int s0 = (int)(bm0 & 2047) + wr * 128;
    const size_t bh = (size_t)b * 16 + h;
#pragma unroll
    for (int it = 0; it < 32; ++it) {
      int nn = it * 2 + (lane >> 5);
      int q = lane & 31;
      int slot = q ^ (nn & 31);
      uint2 dv = *(const uint2*)(T + nn * 256 + slot * 8);
      *(uint2*)(Vt + (bh * 128 + d0 + nn) * 2048 + s0 + 4 * q) = dv;
    }
  }
#undef APHASE
#undef ST_A01
#undef ST_A23
#undef ST_B01
#undef ST_B23
#undef SEG16
#undef PAT
#undef PBT
}

// ---------------------------------------------------------------------------
// Generic GEMM (fp32 out) for the output projection.
__global__ __launch_bounds__(256) void gemm_kernel(
    const ushort_t* __restrict__ A, const ushort_t* __restrict__ Bt,
    float* __restrict__ out, int M, int N, int K) {
  __shared__ char ldsA[16384];
  __shared__ char ldsB[16384];
  const int tid = threadIdx.x;
  const int w = tid >> 6, lane = tid & 63, quad = lane >> 4, l15 = lane & 15;
  const int wm = (w >> 1) * 64, wn = (w & 1) * 64;
  const size_t bm0 = (size_t)blockIdx.y * 128, bn0 = (size_t)blockIdx.x * 128;

  f32x4 zero4 = {0.f, 0.f, 0.f, 0.f};
  f32x4 acc[4][4];
#pragma unroll
  for (int i = 0; i < 4; ++i)
#pragma unroll
    for (int j = 0; j < 4; ++j) acc[i][j] = zero4;

  const int rS = w * 32;
  const int rowOff = lane >> 3;
  const int cph = lane & 7;

  for (int kt = 0; kt < K; kt += 64) {
#pragma unroll
    for (int i = 0; i < 4; ++i) {
      int r0 = rS + i * 8;
      int row = r0 + rowOff;
      int cl = cph ^ (row & 7);
      async16(ldsA + r0 * 128, A + (bm0 + row) * (size_t)K + kt + cl * 8);
      async16(ldsB + r0 * 128, Bt + (bn0 + row) * (size_t)K + kt + cl * 8);
    }
    __syncthreads();
#pragma unroll
    for (int ks = 0; ks < 2; ++ks) {
      bf16x8 af[4], bfv[4];
      int ch = ks * 4 + quad;
#pragma unroll
      for (int tt = 0; tt < 4; ++tt) {
        int ra = wm + tt * 16 + l15;
        af[tt] = *(const bf16x8*)(ldsA + ra * 128 + ((ch ^ (ra & 7)) * 16));
        int rb = wn + tt * 16 + l15;
        bfv[tt] = *(const bf16x8*)(ldsB + rb * 128 + ((ch ^ (rb & 7)) * 16));
      }
#pragma unroll
      for (int i = 0; i < 4; ++i)
#pragma unroll
        for (int j = 0; j < 4; ++j)
          acc[i][j] = __builtin_amdgcn_mfma_f32_16x16x32_bf16(af[i], bfv[j], acc[i][j], 0, 0, 0);
    }
    __syncthreads();
  }
#pragma unroll
  for (int i = 0; i < 4; ++i)
#pragma unroll
    for (int r = 0; r < 4; ++r) {
      size_t m = bm0 + wm + i * 16 + quad * 4 + r;
#pragma unroll
      for (int j = 0; j < 4; ++j) {
        size_t n = bn0 + wn + j * 16 + l15;
        out[m * N + n] = acc[i][j][r];
      }
    }
}

// ---------------------------------------------------------------------------
// Flash attention, causal, + fused adapter attention. 256 threads, q-tile 128,
// k-tile 64. LDS 48KB. Balanced static qt per CU ({u,15-u} pairs).
// Epilogue: normalize oacc, then oacc += (gate*softmax(Q ak^T))@av via MFMA;
// writes bf16 Ob directly.
__global__ __launch_bounds__(256) void flash_kernel(
    const ushort_t* __restrict__ Qb, const ushort_t* __restrict__ Kb,
    const ushort_t* __restrict__ Vt, const ushort_t* __restrict__ akb,
    const ushort_t* __restrict__ avb, const float* __restrict__ gate,
    ushort_t* __restrict__ Ob) {
  __shared__ char ldsK[16384];   // 64 tok x 256B, chunk swz ^(row&15)
  __shared__ char ldsV[16384];   // 128 d x 128B, chunk swz ^(dr&7)
  __shared__ char ldsP[16384];   // loop: P 128q x 128B swz; epilogue: pa[128][40]
  const int tid = threadIdx.x;
  const int w = tid >> 6, lane = tid & 63, quad = lane >> 4, l15 = lane & 15;
  const int idx = blockIdx.x;
  const int p = idx >> 8, c = idx & 255;
  const int u = c >> 4, vv = c & 15;
  const int qt = p ? (15 - u) : u;
  const int hb = (p << 4) | vv;
  const int h = hb >> 1, b = hb & 1;
  const float scale = 0.08838834764831845f;  // 1/sqrt(128)

  bf16x8 ones;
#pragma unroll
  for (int j = 0; j < 8; ++j) ones[j] = (short)0x3F80;

  // Q fragments in registers: 2 m-tiles x 4 d-steps (wave rows w*32..+31)
  bf16x8 qf[2][4];
#pragma unroll
  for (int mt = 0; mt < 2; ++mt) {
    size_t qrow = (size_t)qt * 128 + w * 32 + mt * 16 + l15;
    const ushort_t* base = Qb + ((size_t)b * 2048 + qrow) * 2048 + h * 128 + quad * 8;
#pragma unroll
    for (int ds = 0; ds < 4; ++ds) qf[mt][ds] = *(const bf16x8*)(base + ds * 32);
  }

  f32x4 zero4 = {0.f, 0.f, 0.f, 0.f};
  f32x4 oacc[2][8];
  f32x4 osum[2];
  float mrow[2][4];
#pragma unroll
  for (int mt = 0; mt < 2; ++mt) {
#pragma unroll
    for (int n8 = 0; n8 < 8; ++n8) oacc[mt][n8] = zero4;
    osum[mt] = zero4;
#pragma unroll
    for (int r = 0; r < 4; ++r) mrow[mt][r] = -1e30f;
  }

  const int ktmax = 2 * qt + 1;
  for (int kt = 0; kt <= ktmax; ++kt) {
#pragma unroll
    for (int ii = 0; ii < 4; ++ii) {
      int r0 = w * 16 + ii * 4;
      int row = r0 + (lane >> 4);
      int cl = (lane & 15) ^ (row & 15);
      async16(ldsK + r0 * 256,
              Kb + ((size_t)b * 2048 + kt * 64 + row) * 2048 + h * 128 + cl * 8);
    }
#pragma unroll
    for (int ii = 0; ii < 4; ++ii) {
      int d0 = w * 32 + ii * 8;
      int dr = d0 + (lane >> 3);
      int cl = (lane & 7) ^ (dr & 7);
      async16(ldsV + d0 * 128,
              Vt + ((size_t)(b * 16 + h) * 128 + dr) * 2048 + kt * 64 + cl * 8);
    }
    __syncthreads();

    // S = Q K^T
    f32x4 sacc[2][4];
#pragma unroll
    for (int mt = 0; mt < 2; ++mt)
#pragma unroll
      for (int nt = 0; nt < 4; ++nt) sacc[mt][nt] = zero4;
#pragma unroll
    for (int ds = 0; ds < 4; ++ds) {
      bf16x8 kf[4];
      int ch = ds * 4 + quad;
#pragma unroll
      for (int nt = 0; nt < 4; ++nt) {
        int row = nt * 16 + l15;
        kf[nt] = *(const bf16x8*)(ldsK + row * 256 + ((ch ^ (row & 15)) * 16));
      }
#pragma unroll
      for (int mt = 0; mt < 2; ++mt)
#pragma unroll
        for (int nt = 0; nt < 4; ++nt)
          sacc[mt][nt] = __builtin_amdgcn_mfma_f32_16x16x32_bf16(qf[mt][ds], kf[nt], sacc[mt][nt], 0, 0, 0);
    }

    // online softmax
    const bool domask = (kt >= 2 * qt);
#pragma unroll
    for (int mt = 0; mt < 2; ++mt) {
      float tmax[4] = {-1e30f, -1e30f, -1e30f, -1e30f};
      const int qbase = qt * 128 + w * 32 + mt * 16 + quad * 4;
#pragma unroll
      for (int nt = 0; nt < 4; ++nt) {
        int kg = kt * 64 + nt * 16 + l15;
#pragma unroll
        for (int r = 0; r < 4; ++r) {
          float s = sacc[mt][nt][r] * scale;
          if (domask && kg > qbase + r) s = -1e30f;
          sacc[mt][nt][r] = s;
          tmax[r] = fmaxf(tmax[r], s);
        }
      }
#pragma unroll
      for (int r = 0; r < 4; ++r) {
        float t = rowmax16(tmax[r]);
        float mnew = fmaxf(mrow[mt][r], t);
        float alpha = __expf(mrow[mt][r] - mnew);
        mrow[mt][r] = mnew;
        osum[mt][r] *= alpha;
#pragma unroll
        for (int n8 = 0; n8 < 8; ++n8) oacc[mt][n8][r] *= alpha;
        tmax[r] = mnew;
      }
#pragma unroll
      for (int nt = 0; nt < 4; ++nt) {
        int col = nt * 16 + l15;
#pragma unroll
        for (int r = 0; r < 4; ++r) {
          float pv = __expf(sacc[mt][nt][r] - tmax[r]);
          int prow = w * 32 + mt * 16 + quad * 4 + r;
          int addr = prow * 128 + (((col >> 3) ^ (prow & 7)) * 16) + (col & 7) * 2;
          *(ushort_t*)(ldsP + addr) = f2bf(pv);
        }
      }
    }

    // O += P V ; osum += P 1
#pragma unroll
    for (int ks = 0; ks < 2; ++ks) {
      int ch = ks * 4 + quad;
      bf16x8 pf[2];
#pragma unroll
      for (int mt = 0; mt < 2; ++mt) {
        int prow = w * 32 + mt * 16 + l15;
        pf[mt] = *(const bf16x8*)(ldsP + prow * 128 + ((ch ^ (prow & 7)) * 16));
      }
#pragma unroll
      for (int mt = 0; mt < 2; ++mt)
        osum[mt] = __builtin_amdgcn_mfma_f32_16x16x32_bf16(pf[mt], ones, osum[mt], 0, 0, 0);
#pragma unroll
      for (int n8 = 0; n8 < 8; ++n8) {
        int dr = n8 * 16 + l15;
        bf16x8 vf = *(const bf16x8*)(ldsV + dr * 128 + ((ch ^ (dr & 7)) * 16));
#pragma unroll
        for (int mt = 0; mt < 2; ++mt)
          oacc[mt][n8] = __builtin_amdgcn_mfma_f32_16x16x32_bf16(pf[mt], vf, oacc[mt][n8], 0, 0, 0);
      }
    }
    __syncthreads();
  }

  // ---------------- fused adapter epilogue ----------------
  const float g = gate[h];
  {
    int row = w * 32 + (lane >> 1);
    int koff = 16 + (lane & 1) * 8;
    *(uint4*)(ldsP + row * 80 + koff * 2) = make_uint4(0, 0, 0, 0);
  }
  f32x4 sa[2] = {zero4, zero4};
#pragma unroll
  for (int ds = 0; ds < 4; ++ds) {
    bf16x8 kfa = *(const bf16x8*)(akb + ((size_t)h * 16 + l15) * 128 + ds * 32 + quad * 8);
#pragma unroll
    for (int mt = 0; mt < 2; ++mt)
      sa[mt] = __builtin_amdgcn_mfma_f32_16x16x32_bf16(qf[mt][ds], kfa, sa[mt], 0, 0, 0);
  }
#pragma unroll
  for (int mt = 0; mt < 2; ++mt) {
#pragma unroll
    for (int r = 0; r < 4; ++r) {
      float s = sa[mt][r] * scale;
      if (l15 >= 10) s = -1e30f;
      float mx = rowmax16(s);
      float e = __expf(s - mx);
      float sum = rowsum16(e);
      float pv = g * e / sum;
      int row = w * 32 + mt * 16 + quad * 4 + r;
      *(ushort_t*)(ldsP + row * 80 + l15 * 2) = f2bf(pv);
    }
  }
  bf16x8 paf[2];
#pragma unroll
  for (int mt = 0; mt < 2; ++mt)
    paf[mt] = *(const bf16x8*)(ldsP + (w * 32 + mt * 16 + l15) * 80 + quad * 16);

  // normalize main attention
#pragma unroll
  for (int mt = 0; mt < 2; ++mt) {
    float rl[4];
#pragma unroll
    for (int r = 0; r < 4; ++r) rl[r] = 1.f / osum[mt][r];
#pragma unroll
    for (int n8 = 0; n8 < 8; ++n8)
#pragma unroll
      for (int r = 0; r < 4; ++r) oacc[mt][n8][r] *= rl[r];
  }
  // += pa @ avb ; store bf16
#pragma unroll
  for (int n8 = 0; n8 < 8; ++n8) {
    bf16x8 avf = *(const bf16x8*)(avb + ((size_t)h * 128 + n8 * 16 + l15) * 32 + quad * 8);
#pragma unroll
    for (int mt = 0; mt < 2; ++mt)
      oacc[mt][n8] = __builtin_amdgcn_mfma_f32_16x16x32_bf16(paf[mt], avf, oacc[mt][n8], 0, 0, 0);
  }
#pragma unroll
  for (int mt = 0; mt < 2; ++mt) {
    size_t qb0 = (size_t)qt * 128 + w * 32 + mt * 16 + quad * 4;
#pragma unroll
    for (int n8 = 0; n8 < 8; ++n8) {
      size_t col = (size_t)h * 128 + n8 * 16 + l15;
#pragma unroll
      for (int r = 0; r < 4; ++r)
        Ob[((size_t)b * 2048 + qb0 + r) * 2048 + col] = f2bf(oacc[mt][n8][r]);
    }
  }
}

// ---------------------------------------------------------------------------
extern "C" void kernel_launch(void* const* d_in, const int* in_sizes, int n_in,
                              void* d_out, int out_size, void* d_ws, size_t ws_size,
                              hipStream_t stream) {
  (void)in_sizes; (void)n_in; (void)out_size; (void)ws_size;
  const float* x       = (const float*)d_in[0];
  const float* wq      = (const float*)d_in[1];
  const float* wk      = (const float*)d_in[2];
  const float* wv      = (const float*)d_in[3];
  const float* wo      = (const float*)d_in[4];
  const float* adapter = (const float*)d_in[5];
  const float* gate    = (const float*)d_in[6];
  const float* fc      = (const float*)d_in[7];
  const float* fs      = (const float*)d_in[8];

  char* ws = (char*)d_ws;
  ushort_t* Xb   = (ushort_t*)(ws + 0);           // 16 MB (reused as Ob)
  ushort_t* WtQ  = (ushort_t*)(ws + 16777216);    // 8 MB x4 contiguous
  ushort_t* WtO  = (ushort_t*)(ws + 41943040);
  ushort_t* Qb   = (ushort_t*)(ws + 50331648);    // 16 MB
  ushort_t* Kb   = (ushort_t*)(ws + 67108864);    // 16 MB
  ushort_t* Vt   = (ushort_t*)(ws + 83886080);    // 16 MB
  float*    ak   = (float*)   (ws + 100663296);   // 80 KB
  float*    av   = (float*)   (ws + 100745216);   // 80 KB
  ushort_t* akb  = (ushort_t*)(ws + 100827136);   // 64 KB
  ushort_t* avb  = (ushort_t*)(ws + 100892672);   // 128 KB
  float2*   fcs  = (float2*)  (ws + 101023744);   // 1 MB
  ushort_t* Ob   = Xb;

  cast_x_kernel<<<4096, 256, 0, stream>>>(x, Xb);
  rope_pack_kernel<<<512, 256, 0, stream>>>(fc, fs, fcs);
  transpose_w_kernel<<<dim3(32, 32, 4), 256, 0, stream>>>(wq, wk, wv, wo, WtQ);
  hipMemsetAsync(ak, 0, 163840, stream);
  adapter_kv_kernel<<<dim3(8, 16, 2), 256, 0, stream>>>(adapter, wk, wv, ak, av);
  adapter_pack_kernel<<<256, 256, 0, stream>>>(ak, av, akb, avb);
  gemm_qkv256_kernel<<<dim3(384), 512, 0, stream>>>(Xb, WtQ, Qb, Kb, Vt, fcs);
  flash_kernel<<<512, 256, 0, stream>>>(Qb, Kb, Vt, akb, avb, gate, Ob);
  gemm_kernel<<<dim3(16, 32), 256, 0, stream>>>(Ob, WtO, (float*)d_out, 4096, 2048, 2048);
}

// Round 2
// 444.901 us; speedup vs baseline: 1.0315x; 1.0308x over previous
//
#include <hip/hip_runtime.h>

// ---------------------------------------------------------------------------
// Attention_16698832847178: B=2,S=2048,D=2048,H=16,HD=128,L=10
// R7: retile pipelined GEMM to 128x256 (grid 768 = exactly 3 rounds of 256
// CUs; R6's 256x256 at 384 blocks wasted 1/3 of wall time in a half-idle
// round). Shared 2-phase/K-tile schedule (16 MFMA/phase, counted vmcnt(3),
// setprio, XOR-swizzled LDS, bijective XCD swizzle). wo-GEMM moved onto the
// same K-loop at 256 blocks = exactly 1 round. V-transpose epilogue is the
// proven R5 per-wave 64x64 patch, RoPE epilogue unchanged math.
// ---------------------------------------------------------------------------

typedef unsigned short ushort_t;
typedef unsigned int uint32;
typedef __attribute__((ext_vector_type(8))) short bf16x8;   // 8 bf16 = 4 VGPRs
typedef __attribute__((ext_vector_type(4))) float f32x4;

__device__ __forceinline__ void async16(void* lds, const void* g) {
  __builtin_amdgcn_global_load_lds((const __attribute__((address_space(1))) void*)g,
                                   (__attribute__((address_space(3))) void*)lds,
                                   16, 0, 0);
}
__device__ __forceinline__ ushort_t f2bf(float f) {
  uint32 u = __float_as_uint(f);
  u += 0x7FFFu + ((u >> 16) & 1u);   // round-to-nearest-even
  return (ushort_t)(u >> 16);
}
__device__ __forceinline__ float bf2f(ushort_t b) {
  return __uint_as_float(((uint32)b) << 16);
}
// value from lane^1 via DPP quad_perm [1,0,3,2] (VALU, no LDS)
__device__ __forceinline__ float dpp_xor1(float v) {
  return __int_as_float(__builtin_amdgcn_update_dpp(
      0, __float_as_int(v), 0xB1, 0xf, 0xf, true));
}
#define DPP_MAX(t, ctrl) \
  t = fmaxf(t, __int_as_float(__builtin_amdgcn_update_dpp( \
      0, __float_as_int(t), (ctrl), 0xf, 0xf, true)))
#define DPP_ADD(t, ctrl) \
  t += __int_as_float(__builtin_amdgcn_update_dpp( \
      0, __float_as_int(t), (ctrl), 0xf, 0xf, true))
__device__ __forceinline__ float rowmax16(float t) {
  DPP_MAX(t, 0xB1);   // xor 1
  DPP_MAX(t, 0x4E);   // xor 2
  t = fmaxf(t, __int_as_float(__builtin_amdgcn_ds_swizzle(
      __float_as_int(t), 0x101F)));                  // xor 4
  DPP_MAX(t, 0x128);  // row_ror:8 -> xor 8 (halves uniform after xor1/2/4)
  return t;
}
__device__ __forceinline__ float rowsum16(float t) {
  DPP_ADD(t, 0xB1);
  DPP_ADD(t, 0x4E);
  t += __int_as_float(__builtin_amdgcn_ds_swizzle(__float_as_int(t), 0x101F));
  DPP_ADD(t, 0x128);
  return t;
}

// ---------------------------------------------------------------------------
// cast x (fp32) -> bf16, 8 elements/thread
__global__ __launch_bounds__(256) void cast_x_kernel(const float* __restrict__ x,
                                                     ushort_t* __restrict__ Xb) {
  size_t i = ((size_t)blockIdx.x * 256 + threadIdx.x) * 8;
  float4 a = *(const float4*)(x + i);
  float4 b = *(const float4*)(x + i + 4);
  uint4 o;
  o.x = (uint32)f2bf(a.x) | ((uint32)f2bf(a.y) << 16);
  o.y = (uint32)f2bf(a.z) | ((uint32)f2bf(a.w) << 16);
  o.z = (uint32)f2bf(b.x) | ((uint32)f2bf(b.y) << 16);
  o.w = (uint32)f2bf(b.z) | ((uint32)f2bf(b.w) << 16);
  *(uint4*)(Xb + i) = o;
}

// ---------------------------------------------------------------------------
// pack rope table: fcs[s][fi] = (cos, sin)
__global__ __launch_bounds__(256) void rope_pack_kernel(
    const float* __restrict__ fc, const float* __restrict__ fs,
    float2* __restrict__ fcs) {
  int i = blockIdx.x * 256 + threadIdx.x;   // < 131072
  fcs[i] = make_float2(fc[i], fs[i]);
}

// ---------------------------------------------------------------------------
// W[k][n] fp32 -> Wt[n][k] bf16 (64x64 tiles), dword stores
__global__ __launch_bounds__(256) void transpose_w_kernel(
    const float* __restrict__ w0, const float* __restrict__ w1,
    const float* __restrict__ w2, const float* __restrict__ w3,
    ushort_t* __restrict__ outBase) {
  const float* W = (blockIdx.z == 0) ? w0 : (blockIdx.z == 1) ? w1
                 : (blockIdx.z == 2) ? w2 : w3;
  ushort_t* Wt = outBase + (size_t)blockIdx.z * 4194304;  // 2048*2048
  __shared__ float L[64][65];
  int t = threadIdx.x, tc = t & 63, tr = t >> 6;
  int k0 = blockIdx.x * 64, n0 = blockIdx.y * 64;
  for (int i = 0; i < 16; ++i) {
    int r = i * 4 + tr;
    L[r][tc] = W[(size_t)(k0 + r) * 2048 + n0 + tc];
  }
  __syncthreads();
  int tr8 = t >> 5, tc2 = t & 31;
  for (int i = 0; i < 8; ++i) {
    int r = i * 8 + tr8;
    uint32 pk = (uint32)f2bf(L[2 * tc2][r]) | ((uint32)f2bf(L[2 * tc2 + 1][r]) << 16);
    *(uint32*)(Wt + (size_t)(n0 + r) * 2048 + k0 + 2 * tc2) = pk;
  }
}

// ---------------------------------------------------------------------------
// adapter projections: ak/av[l][n] = sum_k adapter[l][k] * W[k][n]  (fp32)
__global__ __launch_bounds__(256) void adapter_kv_kernel(
    const float* __restrict__ adapter, const float* __restrict__ wk,
    const float* __restrict__ wv, float* __restrict__ ak, float* __restrict__ av) {
  const float* W = blockIdx.z ? wv : wk;
  float* out = blockIdx.z ? av : ak;
  __shared__ float As[10][128];
  int t = threadIdx.x;
  int k0 = blockIdx.y * 128;
  for (int i = t; i < 1280; i += 256)
    As[i >> 7][i & 127] = adapter[(size_t)(i >> 7) * 2048 + k0 + (i & 127)];
  __syncthreads();
  int n = blockIdx.x * 256 + t;
  float acc[10];
#pragma unroll
  for (int l = 0; l < 10; ++l) acc[l] = 0.f;
  for (int kk = 0; kk < 128; ++kk) {
    float wv_ = W[(size_t)(k0 + kk) * 2048 + n];
#pragma unroll
    for (int l = 0; l < 10; ++l) acc[l] += As[l][kk] * wv_;
  }
#pragma unroll
  for (int l = 0; l < 10; ++l) atomicAdd(&out[l * 2048 + n], acc[l]);
}

// ---------------------------------------------------------------------------
// pack ak/av (fp32) into MFMA-fragment-friendly bf16 buffers:
// akb[h][l(16)][d(128)] (l>=10 zero), avb[h][d(128)][l(32)] (l>=10 zero)
__global__ __launch_bounds__(256) void adapter_pack_kernel(
    const float* __restrict__ ak, const float* __restrict__ av,
    ushort_t* __restrict__ akb, ushort_t* __restrict__ avb) {
  int t = blockIdx.x * 256 + threadIdx.x;   // 65536 threads
  if (t < 32768) {
    int h = t >> 11, l = (t >> 7) & 15, d = t & 127;
    akb[t] = (l < 10) ? f2bf(ak[l * 2048 + h * 128 + d]) : (ushort_t)0;
  }
  int h = t >> 12, d = (t >> 5) & 127, l = t & 31;
  avb[t] = (l < 10) ? f2bf(av[l * 2048 + h * 128 + d]) : (ushort_t)0;
}

// ---------------------------------------------------------------------------
// Shared pipelined K-loop: 128x256 tile, BK=64, nt=32 (K=2048 hard-coded),
// 512 threads = 8 waves (2M x 4N), per-wave C = 64x64 (acc 4x4).
// LDS 96KB: A dbuf 2x16KB at [0,32K), B dbuf 2x32KB at [32K,96K).
// Per K-tile, 2 phases of {4 ds_read | stage 3 slots | bar | lgkm0 |
// prio1 16xMFMA prio0 | bar}; B fragments (8 reads) loaded at tile start.
// Staging: p0 -> {A0,A1,B0}(t+1) (opposite LDS parity, always safe);
// p1 -> {B1,B2,B3}(t+2) (same parity, but all B reads of tile t completed
// before p0's end barrier -> race-free). Counted vmcnt(3) once per tile
// (retires tile t+1 completely); vmcnt(0) only at t==nt-2.
// ---------------------------------------------------------------------------
#define QK_BARX() asm volatile("s_barrier" ::: "memory")
#define QK_LGKM0() asm volatile("s_waitcnt lgkmcnt(0)" ::: "memory")

__device__ __forceinline__ void kloop_128x256(
    char* lds, const ushort_t* __restrict__ A, const ushort_t* __restrict__ Bt,
    size_t bm0, size_t bn0, f32x4 (&acc)[4][4]) {
  const int tid = (int)threadIdx.x;
  const int w = tid >> 6, lane = tid & 63, quad = lane >> 4, l15 = lane & 15;
  const int wr = (w >> 2) * 64, wc = (w & 3) * 64;
  const int nt = 32;
  char* const pA0 = lds;
  char* const pA1 = lds + 16384;
  char* const pB0 = lds + 32768;
  char* const pB1 = lds + 65536;

#define PAT(T) (((T) & 1) ? pA1 : pA0)
#define PBT(T) (((T) & 1) ? pB1 : pB0)
// stage one 64-row slot (8KB): 8 rows/wave, linear LDS dest (wave-uniform
// base + lane*16); XOR chunk swizzle applied on the GLOBAL source address so
// reads use chunk ^ (row&7).
#define SEGL(OP, LDSB, GROW, T)                                                \
  do {                                                                         \
    int rr_ = w * 8 + (lane >> 3);                                             \
    int cl_ = (lane & 7) ^ (rr_ & 7);                                          \
    async16((LDSB) + w * 1024,                                                 \
            (OP) + ((GROW) + (size_t)rr_) * 2048 + (size_t)((T) * 64 + cl_ * 8)); \
  } while (0)
#define ST_A(T)                                                                \
  do { if ((T) < nt) { SEGL(A, PAT(T), bm0, (T));                              \
                       SEGL(A, PAT(T) + 8192, bm0 + 64, (T)); } } while (0)
#define ST_B0(T)                                                               \
  do { if ((T) < nt) SEGL(Bt, PBT(T), bn0, (T)); } while (0)
#define ST_B123(T)                                                             \
  do { if ((T) < nt) { SEGL(Bt, PBT(T) + 8192,  bn0 + 64,  (T));               \
                       SEGL(Bt, PBT(T) + 16384, bn0 + 128, (T));               \
                       SEGL(Bt, PBT(T) + 24576, bn0 + 192, (T)); } } while (0)

  // prologue: tile0 complete (6 slots) + B123(1) in flight = steady state
  ST_A(0); ST_B0(0); ST_B123(0); ST_B123(1);
  asm volatile("s_waitcnt vmcnt(3)" ::: "memory");
  QK_BARX();

#pragma unroll 2
  for (int t = 0; t < nt; ++t) {
    const char* pA = PAT(t);
    const char* pB = PBT(t);
    bf16x8 bfv[4][2];   // whole wave B-slice in registers (retires B at p0)
#pragma unroll
    for (int j = 0; j < 4; ++j) {
      int brow = wc + j * 16 + l15;
#pragma unroll
      for (int ks = 0; ks < 2; ++ks)
        bfv[j][ks] = *(const bf16x8*)(pB + brow * 128 +
                                      (((ks * 4 + quad) ^ (brow & 7)) * 16));
    }
#pragma unroll
    for (int ph = 0; ph < 2; ++ph) {
      bf16x8 af[2][2];
#pragma unroll
      for (int ii = 0; ii < 2; ++ii) {
        int arow = wr + (ph * 2 + ii) * 16 + l15;
#pragma unroll
        for (int ks = 0; ks < 2; ++ks)
          af[ii][ks] = *(const bf16x8*)(pA + arow * 128 +
                                        (((ks * 4 + quad) ^ (arow & 7)) * 16));
      }
      if (ph == 0) { ST_A(t + 1); ST_B0(t + 1); }
      else         { ST_B123(t + 2); }
      QK_BARX();
      QK_LGKM0();
      __builtin_amdgcn_s_setprio(1);
#pragma unroll
      for (int ks = 0; ks < 2; ++ks)
#pragma unroll
        for (int ii = 0; ii < 2; ++ii)
#pragma unroll
          for (int j = 0; j < 4; ++j)
            acc[ph * 2 + ii][j] = __builtin_amdgcn_mfma_f32_16x16x32_bf16(
                af[ii][ks], bfv[j][ks], acc[ph * 2 + ii][j], 0, 0, 0);
      __builtin_amdgcn_s_setprio(0);
      if (ph == 1) {
        if (t == nt - 2) asm volatile("s_waitcnt vmcnt(0)" ::: "memory");
        else             asm volatile("s_waitcnt vmcnt(3)" ::: "memory");
      }
      QK_BARX();
    }
  }
#undef PAT
#undef PBT
#undef SEGL
#undef ST_A
#undef ST_B0
#undef ST_B123
}

// ---------------------------------------------------------------------------
// Fused QKV GEMM: C[4096,6144] = Xb[4096,2048] x WtQKV[6144,2048]^T.
// Grid 768 (32 M x 24 N) = exactly 3 rounds of 256 CUs.
// Q,K segments: RoPE fused. V segment: per-wave 64x64 LDS transpose -> Vt.
__global__ __launch_bounds__(512, 2) void gemm_qkv128_kernel(
    const ushort_t* __restrict__ A, const ushort_t* __restrict__ Bt,
    ushort_t* __restrict__ outQ, ushort_t* __restrict__ outK,
    ushort_t* __restrict__ Vt, const float2* __restrict__ fcs) {
  __shared__ char lds[98304];
  const int tid = (int)threadIdx.x;
  const int w = tid >> 6, lane = tid & 63, quad = lane >> 4, l15 = lane & 15;
  const int wr = (w >> 2) * 64, wc = (w & 3) * 64;

  // bijective XCD swizzle: 768 wgs = 8 XCDs x 96; each XCD gets 3 contiguous
  // B-panels (3MB, L2-resident) x all 32 M-tiles.
  const int wg = ((int)blockIdx.x & 7) * 96 + ((int)blockIdx.x >> 3);
  const size_t bm0 = (size_t)(wg & 31) * 128;
  const size_t bn0 = (size_t)(wg >> 5) * 256;

  f32x4 acc[4][4];
  f32x4 z4 = {0.f, 0.f, 0.f, 0.f};
#pragma unroll
  for (int i = 0; i < 4; ++i)
#pragma unroll
    for (int j = 0; j < 4; ++j) acc[i][j] = z4;

  kloop_128x256(lds, A, Bt, bm0, bn0, acc);

  const int seg = (int)(bn0 >> 11);   // 0=Q, 1=K, 2=V (256 divides 2048)
  if (seg < 2) {
    ushort_t* ob = seg ? outK : outQ;
#pragma unroll
    for (int i = 0; i < 4; ++i)
#pragma unroll
      for (int r = 0; r < 4; ++r) {
        size_t m = bm0 + wr + i * 16 + quad * 4 + r;
        int s = (int)(m & 2047);
#pragma unroll
        for (int j = 0; j < 4; ++j) {
          size_t n = (bn0 + wc + j * 16 + l15) & 2047;
          float v = acc[i][j][r];
          float v2 = dpp_xor1(v);             // RoPE pair partner (col n^1)
          int fi = ((int)n & 127) >> 1;
          float2 cs = fcs[s * 64 + fi];
          v = (lane & 1) ? (v2 * cs.y + v * cs.x) : (v * cs.x - v2 * cs.y);
          ob[m * 2048 + n] = f2bf(v);
        }
      }
  } else {
    // V segment: per-wave 64(n) x 64(m) transpose patch through LDS
    // (proven R5 pattern; per-wave private patch after the final barrier,
    // so no extra sync needed). dword slot swizzled: slot = md ^ (nn&31).
    char* T = lds + w * 8192;
#pragma unroll
    for (int i = 0; i < 4; ++i)
#pragma unroll
      for (int j = 0; j < 4; ++j) {
        int nn = j * 16 + l15;
        int md0 = i * 8 + quad * 2;
        uint32 p01 = (uint32)f2bf(acc[i][j][0]) | ((uint32)f2bf(acc[i][j][1]) << 16);
        uint32 p23 = (uint32)f2bf(acc[i][j][2]) | ((uint32)f2bf(acc[i][j][3]) << 16);
        *(uint32*)(T + nn * 128 + ((md0 ^ (nn & 31)) * 4)) = p01;
        *(uint32*)(T + nn * 128 + (((md0 + 1) ^ (nn & 31)) * 4)) = p23;
      }
    const int b = (int)(bm0 >> 11);
    const int s0 = (int)(bm0 & 2047) + wr;
    const int n2 = (int)(bn0 & 2047) + wc;
#pragma unroll
    for (int it = 0; it < 32; ++it) {
      int row = it * 2 + (lane >> 5);
      int pp = lane & 31;
      uint32 dv = *(const uint32*)(T + row * 128 + pp * 4);
      int md = pp ^ (row & 31);
      int nloc = n2 + row;
      size_t bh = (size_t)b * 16 + (nloc >> 7);
      *(uint32*)(Vt + (bh * 128 + (size_t)(nloc & 127)) * 2048 + s0 + 2 * md) = dv;
    }
  }
}

// ---------------------------------------------------------------------------
// Output projection on the same K-loop: out[4096,2048] fp32 = Ob x WtO^T.
// Grid 256 (32 M x 8 N) = exactly 1 round of 256 CUs.
__global__ __launch_bounds__(512, 2) void gemm_wo_kernel(
    const ushort_t* __restrict__ A, const ushort_t* __restrict__ Bt,
    float* __restrict__ out) {
  __shared__ char lds[98304];
  const int tid = (int)threadIdx.x;
  const int w = tid >> 6, lane = tid & 63, quad = lane >> 4, l15 = lane & 15;
  const int wr = (w >> 2) * 64, wc = (w & 3) * 64;

  const int wg = ((int)blockIdx.x & 7) * 32 + ((int)blockIdx.x >> 3);
  const size_t bm0 = (size_t)(wg & 31) * 128;
  const size_t bn0 = (size_t)(wg >> 5) * 256;

  f32x4 acc[4][4];
  f32x4 z4 = {0.f, 0.f, 0.f, 0.f};
#pragma unroll
  for (int i = 0; i < 4; ++i)
#pragma unroll
    for (int j = 0; j < 4; ++j) acc[i][j] = z4;

  kloop_128x256(lds, A, Bt, bm0, bn0, acc);

#pragma unroll
  for (int i = 0; i < 4; ++i)
#pragma unroll
    for (int r = 0; r < 4; ++r) {
      size_t m = bm0 + wr + i * 16 + quad * 4 + r;
#pragma unroll
      for (int j = 0; j < 4; ++j) {
        size_t n = bn0 + wc + j * 16 + l15;
        out[m * 2048 + n] = acc[i][j][r];
      }
    }
}

// ---------------------------------------------------------------------------
// Flash attention, causal, + fused adapter attention. 256 threads, q-tile 128,
// k-tile 64. LDS 48KB. Balanced static qt per CU ({u,15-u} pairs).
// Epilogue: normalize oacc, then oacc += (gate*softmax(Q ak^T))@av via MFMA;
// writes bf16 Ob directly.
__global__ __launch_bounds__(256) void flash_kernel(
    const ushort_t* __restrict__ Qb, const ushort_t* __restrict__ Kb,
    const ushort_t* __restrict__ Vt, const ushort_t* __restrict__ akb,
    const ushort_t* __restrict__ avb, const float* __restrict__ gate,
    ushort_t* __restrict__ Ob) {
  __shared__ char ldsK[16384];   // 64 tok x 256B, chunk swz ^(row&15)
  __shared__ char ldsV[16384];   // 128 d x 128B, chunk swz ^(dr&7)
  __shared__ char ldsP[16384];   // loop: P 128q x 128B swz; epilogue: pa[128][40]
  const int tid = threadIdx.x;
  const int w = tid >> 6, lane = tid & 63, quad = lane >> 4, l15 = lane & 15;
  const int idx = blockIdx.x;
  const int p = idx >> 8, c = idx & 255;
  const int u = c >> 4, vv = c & 15;
  const int qt = p ? (15 - u) : u;
  const int hb = (p << 4) | vv;
  const int h = hb >> 1, b = hb & 1;
  const float scale = 0.08838834764831845f;  // 1/sqrt(128)

  bf16x8 ones;
#pragma unroll
  for (int j = 0; j < 8; ++j) ones[j] = (short)0x3F80;

  // Q fragments in registers: 2 m-tiles x 4 d-steps (wave rows w*32..+31)
  bf16x8 qf[2][4];
#pragma unroll
  for (int mt = 0; mt < 2; ++mt) {
    size_t qrow = (size_t)qt * 128 + w * 32 + mt * 16 + l15;
    const ushort_t* base = Qb + ((size_t)b * 2048 + qrow) * 2048 + h * 128 + quad * 8;
#pragma unroll
    for (int ds = 0; ds < 4; ++ds) qf[mt][ds] = *(const bf16x8*)(base + ds * 32);
  }

  f32x4 zero4 = {0.f, 0.f, 0.f, 0.f};
  f32x4 oacc[2][8];
  f32x4 osum[2];
  float mrow[2][4];
#pragma unroll
  for (int mt = 0; mt < 2; ++mt) {
#pragma unroll
    for (int n8 = 0; n8 < 8; ++n8) oacc[mt][n8] = zero4;
    osum[mt] = zero4;
#pragma unroll
    for (int r = 0; r < 4; ++r) mrow[mt][r] = -1e30f;
  }

  const int ktmax = 2 * qt + 1;
  for (int kt = 0; kt <= ktmax; ++kt) {
#pragma unroll
    for (int ii = 0; ii < 4; ++ii) {
      int r0 = w * 16 + ii * 4;
      int row = r0 + (lane >> 4);
      int cl = (lane & 15) ^ (row & 15);
      async16(ldsK + r0 * 256,
              Kb + ((size_t)b * 2048 + kt * 64 + row) * 2048 + h * 128 + cl * 8);
    }
#pragma unroll
    for (int ii = 0; ii < 4; ++ii) {
      int d0 = w * 32 + ii * 8;
      int dr = d0 + (lane >> 3);
      int cl = (lane & 7) ^ (dr & 7);
      async16(ldsV + d0 * 128,
              Vt + ((size_t)(b * 16 + h) * 128 + dr) * 2048 + kt * 64 + cl * 8);
    }
    __syncthreads();

    // S = Q K^T
    f32x4 sacc[2][4];
#pragma unroll
    for (int mt = 0; mt < 2; ++mt)
#pragma unroll
      for (int nt = 0; nt < 4; ++nt) sacc[mt][nt] = zero4;
#pragma unroll
    for (int ds = 0; ds < 4; ++ds) {
      bf16x8 kf[4];
      int ch = ds * 4 + quad;
#pragma unroll
      for (int nt = 0; nt < 4; ++nt) {
        int row = nt * 16 + l15;
        kf[nt] = *(const bf16x8*)(ldsK + row * 256 + ((ch ^ (row & 15)) * 16));
      }
#pragma unroll
      for (int mt = 0; mt < 2; ++mt)
#pragma unroll
        for (int nt = 0; nt < 4; ++nt)
          sacc[mt][nt] = __builtin_amdgcn_mfma_f32_16x16x32_bf16(qf[mt][ds], kf[nt], sacc[mt][nt], 0, 0, 0);
    }

    // online softmax
    const bool domask = (kt >= 2 * qt);
#pragma unroll
    for (int mt = 0; mt < 2; ++mt) {
      float tmax[4] = {-1e30f, -1e30f, -1e30f, -1e30f};
      const int qbase = qt * 128 + w * 32 + mt * 16 + quad * 4;
#pragma unroll
      for (int nt = 0; nt < 4; ++nt) {
        int kg = kt * 64 + nt * 16 + l15;
#pragma unroll
        for (int r = 0; r < 4; ++r) {
          float s = sacc[mt][nt][r] * scale;
          if (domask && kg > qbase + r) s = -1e30f;
          sacc[mt][nt][r] = s;
          tmax[r] = fmaxf(tmax[r], s);
        }
      }
#pragma unroll
      for (int r = 0; r < 4; ++r) {
        float t = rowmax16(tmax[r]);
        float mnew = fmaxf(mrow[mt][r], t);
        float alpha = __expf(mrow[mt][r] - mnew);
        mrow[mt][r] = mnew;
        osum[mt][r] *= alpha;
#pragma unroll
        for (int n8 = 0; n8 < 8; ++n8) oacc[mt][n8][r] *= alpha;
        tmax[r] = mnew;
      }
#pragma unroll
      for (int nt = 0; nt < 4; ++nt) {
        int col = nt * 16 + l15;
#pragma unroll
        for (int r = 0; r < 4; ++r) {
          float pv = __expf(sacc[mt][nt][r] - tmax[r]);
          int prow = w * 32 + mt * 16 + quad * 4 + r;
          int addr = prow * 128 + (((col >> 3) ^ (prow & 7)) * 16) + (col & 7) * 2;
          *(ushort_t*)(ldsP + addr) = f2bf(pv);
        }
      }
    }

    // O += P V ; osum += P 1
#pragma unroll
    for (int ks = 0; ks < 2; ++ks) {
      int ch = ks * 4 + quad;
      bf16x8 pf[2];
#pragma unroll
      for (int mt = 0; mt < 2; ++mt) {
        int prow = w * 32 + mt * 16 + l15;
        pf[mt] = *(const bf16x8*)(ldsP + prow * 128 + ((ch ^ (prow & 7)) * 16));
      }
#pragma unroll
      for (int mt = 0; mt < 2; ++mt)
        osum[mt] = __builtin_amdgcn_mfma_f32_16x16x32_bf16(pf[mt], ones, osum[mt], 0, 0, 0);
#pragma unroll
      for (int n8 = 0; n8 < 8; ++n8) {
        int dr = n8 * 16 + l15;
        bf16x8 vf = *(const bf16x8*)(ldsV + dr * 128 + ((ch ^ (dr & 7)) * 16));
#pragma unroll
        for (int mt = 0; mt < 2; ++mt)
          oacc[mt][n8] = __builtin_amdgcn_mfma_f32_16x16x32_bf16(pf[mt], vf, oacc[mt][n8], 0, 0, 0);
      }
    }
    __syncthreads();
  }

  // ---------------- fused adapter epilogue ----------------
  const float g = gate[h];
  {
    int row = w * 32 + (lane >> 1);
    int koff = 16 + (lane & 1) * 8;
    *(uint4*)(ldsP + row * 80 + koff * 2) = make_uint4(0, 0, 0, 0);
  }
  f32x4 sa[2] = {zero4, zero4};
#pragma unroll
  for (int ds = 0; ds < 4; ++ds) {
    bf16x8 kfa = *(const bf16x8*)(akb + ((size_t)h * 16 + l15) * 128 + ds * 32 + quad * 8);
#pragma unroll
    for (int mt = 0; mt < 2; ++mt)
      sa[mt] = __builtin_amdgcn_mfma_f32_16x16x32_bf16(qf[mt][ds], kfa, sa[mt], 0, 0, 0);
  }
#pragma unroll
  for (int mt = 0; mt < 2; ++mt) {
#pragma unroll
    for (int r = 0; r < 4; ++r) {
      float s = sa[mt][r] * scale;
      if (l15 >= 10) s = -1e30f;
      float mx = rowmax16(s);
      float e = __expf(s - mx);
      float sum = rowsum16(e);
      float pv = g * e / sum;
      int row = w * 32 + mt * 16 + quad * 4 + r;
      *(ushort_t*)(ldsP + row * 80 + l15 * 2) = f2bf(pv);
    }
  }
  bf16x8 paf[2];
#pragma unroll
  for (int mt = 0; mt < 2; ++mt)
    paf[mt] = *(const bf16x8*)(ldsP + (w * 32 + mt * 16 + l15) * 80 + quad * 16);

  // normalize main attention
#pragma unroll
  for (int mt = 0; mt < 2; ++mt) {
    float rl[4];
#pragma unroll
    for (int r = 0; r < 4; ++r) rl[r] = 1.f / osum[mt][r];
#pragma unroll
    for (int n8 = 0; n8 < 8; ++n8)
#pragma unroll
      for (int r = 0; r < 4; ++r) oacc[mt][n8][r] *= rl[r];
  }
  // += pa @ avb ; store bf16
#pragma unroll
  for (int n8 = 0; n8 < 8; ++n8) {
    bf16x8 avf = *(const bf16x8*)(avb + ((size_t)h * 128 + n8 * 16 + l15) * 32 + quad * 8);
#pragma unroll
    for (int mt = 0; mt < 2; ++mt)
      oacc[mt][n8] = __builtin_amdgcn_mfma_f32_16x16x32_bf16(paf[mt], avf, oacc[mt][n8], 0, 0, 0);
  }
#pragma unroll
  for (int mt = 0; mt < 2; ++mt) {
    size_t qb0 = (size_t)qt * 128 + w * 32 + mt * 16 + quad * 4;
#pragma unroll
    for (int n8 = 0; n8 < 8; ++n8) {
      size_t col = (size_t)h * 128 + n8 * 16 + l15;
#pragma unroll
      for (int r = 0; r < 4; ++r)
        Ob[((size_t)b * 2048 + qb0 + r) * 2048 + col] = f2bf(oacc[mt][n8][r]);
    }
  }
}

// ---------------------------------------------------------------------------
extern "C" void kernel_launch(void* const* d_in, const int* in_sizes, int n_in,
                              void* d_out, int out_size, void* d_ws, size_t ws_size,
                              hipStream_t stream) {
  (void)in_sizes; (void)n_in; (void)out_size; (void)ws_size;
  const float* x       = (const float*)d_in[0];
  const float* wq      = (const float*)d_in[1];
  const float* wk      = (const float*)d_in[2];
  const float* wv      = (const float*)d_in[3];
  const float* wo      = (const float*)d_in[4];
  const float* adapter = (const float*)d_in[5];
  const float* gate    = (const float*)d_in[6];
  const float* fc      = (const float*)d_in[7];
  const float* fs      = (const float*)d_in[8];

  char* ws = (char*)d_ws;
  ushort_t* Xb   = (ushort_t*)(ws + 0);           // 16 MB (reused as Ob)
  ushort_t* WtQ  = (ushort_t*)(ws + 16777216);    // 8 MB x4 contiguous
  ushort_t* WtO  = (ushort_t*)(ws + 41943040);
  ushort_t* Qb   = (ushort_t*)(ws + 50331648);    // 16 MB
  ushort_t* Kb   = (ushort_t*)(ws + 67108864);    // 16 MB
  ushort_t* Vt   = (ushort_t*)(ws + 83886080);    // 16 MB
  float*    ak   = (float*)   (ws + 100663296);   // 80 KB
  float*    av   = (float*)   (ws + 100745216);   // 80 KB
  ushort_t* akb  = (ushort_t*)(ws + 100827136);   // 64 KB
  ushort_t* avb  = (ushort_t*)(ws + 100892672);   // 128 KB
  float2*   fcs  = (float2*)  (ws + 101023744);   // 1 MB
  ushort_t* Ob   = Xb;

  cast_x_kernel<<<4096, 256, 0, stream>>>(x, Xb);
  rope_pack_kernel<<<512, 256, 0, stream>>>(fc, fs, fcs);
  transpose_w_kernel<<<dim3(32, 32, 4), 256, 0, stream>>>(wq, wk, wv, wo, WtQ);
  hipMemsetAsync(ak, 0, 163840, stream);
  adapter_kv_kernel<<<dim3(8, 16, 2), 256, 0, stream>>>(adapter, wk, wv, ak, av);
  adapter_pack_kernel<<<256, 256, 0, stream>>>(ak, av, akb, avb);
  gemm_qkv128_kernel<<<dim3(768), 512, 0, stream>>>(Xb, WtQ, Qb, Kb, Vt, fcs);
  flash_kernel<<<512, 256, 0, stream>>>(Qb, Kb, Vt, akb, avb, gate, Ob);
  gemm_wo_kernel<<<dim3(256), 512, 0, stream>>>(Ob, WtO, (float*)d_out);
}

// Round 3
// 432.624 us; speedup vs baseline: 1.0608x; 1.0284x over previous
//
#include <hip/hip_runtime.h>

// ---------------------------------------------------------------------------
// Attention_16698832847178: B=2,S=2048,D=2048,H=16,HD=128,L=10
// R8: flash rewrite for occupancy + VALU. q-tile 64 (mt=1/wave), grid 1024,
// LDS 40KB -> 4 blocks/CU, launch_bounds(256,4) -> 16 waves/CU. Defer-max
// (THR=8) skips the online-softmax rescale most k-tiles; P-store packed via
// dpp_xor1 + v_cvt_pk_bf16_f32 (even lanes store dwords). Co-resident qt sums
// constant (62) per CU. GEMMs unchanged from R7 (128x256 pipelined).
// ---------------------------------------------------------------------------

typedef unsigned short ushort_t;
typedef unsigned int uint32;
typedef __attribute__((ext_vector_type(8))) short bf16x8;   // 8 bf16 = 4 VGPRs
typedef __attribute__((ext_vector_type(4))) float f32x4;

__device__ __forceinline__ void async16(void* lds, const void* g) {
  __builtin_amdgcn_global_load_lds((const __attribute__((address_space(1))) void*)g,
                                   (__attribute__((address_space(3))) void*)lds,
                                   16, 0, 0);
}
__device__ __forceinline__ ushort_t f2bf(float f) {
  uint32 u = __float_as_uint(f);
  u += 0x7FFFu + ((u >> 16) & 1u);   // round-to-nearest-even
  return (ushort_t)(u >> 16);
}
__device__ __forceinline__ float bf2f(ushort_t b) {
  return __uint_as_float(((uint32)b) << 16);
}
// value from lane^1 via DPP quad_perm [1,0,3,2] (VALU, no LDS)
__device__ __forceinline__ float dpp_xor1(float v) {
  return __int_as_float(__builtin_amdgcn_update_dpp(
      0, __float_as_int(v), 0xB1, 0xf, 0xf, true));
}
#define DPP_MAX(t, ctrl) \
  t = fmaxf(t, __int_as_float(__builtin_amdgcn_update_dpp( \
      0, __float_as_int(t), (ctrl), 0xf, 0xf, true)))
#define DPP_ADD(t, ctrl) \
  t += __int_as_float(__builtin_amdgcn_update_dpp( \
      0, __float_as_int(t), (ctrl), 0xf, 0xf, true))
__device__ __forceinline__ float rowmax16(float t) {
  DPP_MAX(t, 0xB1);   // xor 1
  DPP_MAX(t, 0x4E);   // xor 2
  t = fmaxf(t, __int_as_float(__builtin_amdgcn_ds_swizzle(
      __float_as_int(t), 0x101F)));                  // xor 4
  DPP_MAX(t, 0x128);  // row_ror:8 -> xor 8 (halves uniform after xor1/2/4)
  return t;
}
__device__ __forceinline__ float rowsum16(float t) {
  DPP_ADD(t, 0xB1);
  DPP_ADD(t, 0x4E);
  t += __int_as_float(__builtin_amdgcn_ds_swizzle(__float_as_int(t), 0x101F));
  DPP_ADD(t, 0x128);
  return t;
}

// ---------------------------------------------------------------------------
// cast x (fp32) -> bf16, 8 elements/thread
__global__ __launch_bounds__(256) void cast_x_kernel(const float* __restrict__ x,
                                                     ushort_t* __restrict__ Xb) {
  size_t i = ((size_t)blockIdx.x * 256 + threadIdx.x) * 8;
  float4 a = *(const float4*)(x + i);
  float4 b = *(const float4*)(x + i + 4);
  uint4 o;
  o.x = (uint32)f2bf(a.x) | ((uint32)f2bf(a.y) << 16);
  o.y = (uint32)f2bf(a.z) | ((uint32)f2bf(a.w) << 16);
  o.z = (uint32)f2bf(b.x) | ((uint32)f2bf(b.y) << 16);
  o.w = (uint32)f2bf(b.z) | ((uint32)f2bf(b.w) << 16);
  *(uint4*)(Xb + i) = o;
}

// ---------------------------------------------------------------------------
// pack rope table: fcs[s][fi] = (cos, sin)
__global__ __launch_bounds__(256) void rope_pack_kernel(
    const float* __restrict__ fc, const float* __restrict__ fs,
    float2* __restrict__ fcs) {
  int i = blockIdx.x * 256 + threadIdx.x;   // < 131072
  fcs[i] = make_float2(fc[i], fs[i]);
}

// ---------------------------------------------------------------------------
// W[k][n] fp32 -> Wt[n][k] bf16 (64x64 tiles), dword stores
__global__ __launch_bounds__(256) void transpose_w_kernel(
    const float* __restrict__ w0, const float* __restrict__ w1,
    const float* __restrict__ w2, const float* __restrict__ w3,
    ushort_t* __restrict__ outBase) {
  const float* W = (blockIdx.z == 0) ? w0 : (blockIdx.z == 1) ? w1
                 : (blockIdx.z == 2) ? w2 : w3;
  ushort_t* Wt = outBase + (size_t)blockIdx.z * 4194304;  // 2048*2048
  __shared__ float L[64][65];
  int t = threadIdx.x, tc = t & 63, tr = t >> 6;
  int k0 = blockIdx.x * 64, n0 = blockIdx.y * 64;
  for (int i = 0; i < 16; ++i) {
    int r = i * 4 + tr;
    L[r][tc] = W[(size_t)(k0 + r) * 2048 + n0 + tc];
  }
  __syncthreads();
  int tr8 = t >> 5, tc2 = t & 31;
  for (int i = 0; i < 8; ++i) {
    int r = i * 8 + tr8;
    uint32 pk = (uint32)f2bf(L[2 * tc2][r]) | ((uint32)f2bf(L[2 * tc2 + 1][r]) << 16);
    *(uint32*)(Wt + (size_t)(n0 + r) * 2048 + k0 + 2 * tc2) = pk;
  }
}

// ---------------------------------------------------------------------------
// adapter projections: ak/av[l][n] = sum_k adapter[l][k] * W[k][n]  (fp32)
__global__ __launch_bounds__(256) void adapter_kv_kernel(
    const float* __restrict__ adapter, const float* __restrict__ wk,
    const float* __restrict__ wv, float* __restrict__ ak, float* __restrict__ av) {
  const float* W = blockIdx.z ? wv : wk;
  float* out = blockIdx.z ? av : ak;
  __shared__ float As[10][128];
  int t = threadIdx.x;
  int k0 = blockIdx.y * 128;
  for (int i = t; i < 1280; i += 256)
    As[i >> 7][i & 127] = adapter[(size_t)(i >> 7) * 2048 + k0 + (i & 127)];
  __syncthreads();
  int n = blockIdx.x * 256 + t;
  float acc[10];
#pragma unroll
  for (int l = 0; l < 10; ++l) acc[l] = 0.f;
  for (int kk = 0; kk < 128; ++kk) {
    float wv_ = W[(size_t)(k0 + kk) * 2048 + n];
#pragma unroll
    for (int l = 0; l < 10; ++l) acc[l] += As[l][kk] * wv_;
  }
#pragma unroll
  for (int l = 0; l < 10; ++l) atomicAdd(&out[l * 2048 + n], acc[l]);
}

// ---------------------------------------------------------------------------
// pack ak/av (fp32) into MFMA-fragment-friendly bf16 buffers:
// akb[h][l(16)][d(128)] (l>=10 zero), avb[h][d(128)][l(32)] (l>=10 zero)
__global__ __launch_bounds__(256) void adapter_pack_kernel(
    const float* __restrict__ ak, const float* __restrict__ av,
    ushort_t* __restrict__ akb, ushort_t* __restrict__ avb) {
  int t = blockIdx.x * 256 + threadIdx.x;   // 65536 threads
  if (t < 32768) {
    int h = t >> 11, l = (t >> 7) & 15, d = t & 127;
    akb[t] = (l < 10) ? f2bf(ak[l * 2048 + h * 128 + d]) : (ushort_t)0;
  }
  int h = t >> 12, d = (t >> 5) & 127, l = t & 31;
  avb[t] = (l < 10) ? f2bf(av[l * 2048 + h * 128 + d]) : (ushort_t)0;
}

// ---------------------------------------------------------------------------
// Shared pipelined K-loop: 128x256 tile, BK=64, nt=32 (K=2048 hard-coded),
// 512 threads = 8 waves (2M x 4N), per-wave C = 64x64 (acc 4x4).
// LDS 96KB: A dbuf 2x16KB at [0,32K), B dbuf 2x32KB at [32K,96K).
// ---------------------------------------------------------------------------
#define QK_BARX() asm volatile("s_barrier" ::: "memory")
#define QK_LGKM0() asm volatile("s_waitcnt lgkmcnt(0)" ::: "memory")

__device__ __forceinline__ void kloop_128x256(
    char* lds, const ushort_t* __restrict__ A, const ushort_t* __restrict__ Bt,
    size_t bm0, size_t bn0, f32x4 (&acc)[4][4]) {
  const int tid = (int)threadIdx.x;
  const int w = tid >> 6, lane = tid & 63, quad = lane >> 4, l15 = lane & 15;
  const int wr = (w >> 2) * 64, wc = (w & 3) * 64;
  const int nt = 32;
  char* const pA0 = lds;
  char* const pA1 = lds + 16384;
  char* const pB0 = lds + 32768;
  char* const pB1 = lds + 65536;

#define PAT(T) (((T) & 1) ? pA1 : pA0)
#define PBT(T) (((T) & 1) ? pB1 : pB0)
#define SEGL(OP, LDSB, GROW, T)                                                \
  do {                                                                         \
    int rr_ = w * 8 + (lane >> 3);                                             \
    int cl_ = (lane & 7) ^ (rr_ & 7);                                          \
    async16((LDSB) + w * 1024,                                                 \
            (OP) + ((GROW) + (size_t)rr_) * 2048 + (size_t)((T) * 64 + cl_ * 8)); \
  } while (0)
#define ST_A(T)                                                                \
  do { if ((T) < nt) { SEGL(A, PAT(T), bm0, (T));                              \
                       SEGL(A, PAT(T) + 8192, bm0 + 64, (T)); } } while (0)
#define ST_B0(T)                                                               \
  do { if ((T) < nt) SEGL(Bt, PBT(T), bn0, (T)); } while (0)
#define ST_B123(T)                                                             \
  do { if ((T) < nt) { SEGL(Bt, PBT(T) + 8192,  bn0 + 64,  (T));               \
                       SEGL(Bt, PBT(T) + 16384, bn0 + 128, (T));               \
                       SEGL(Bt, PBT(T) + 24576, bn0 + 192, (T)); } } while (0)

  // prologue: tile0 complete (6 slots) + B123(1) in flight = steady state
  ST_A(0); ST_B0(0); ST_B123(0); ST_B123(1);
  asm volatile("s_waitcnt vmcnt(3)" ::: "memory");
  QK_BARX();

#pragma unroll 2
  for (int t = 0; t < nt; ++t) {
    const char* pA = PAT(t);
    const char* pB = PBT(t);
    bf16x8 bfv[4][2];   // whole wave B-slice in registers (retires B at p0)
#pragma unroll
    for (int j = 0; j < 4; ++j) {
      int brow = wc + j * 16 + l15;
#pragma unroll
      for (int ks = 0; ks < 2; ++ks)
        bfv[j][ks] = *(const bf16x8*)(pB + brow * 128 +
                                      (((ks * 4 + quad) ^ (brow & 7)) * 16));
    }
#pragma unroll
    for (int ph = 0; ph < 2; ++ph) {
      bf16x8 af[2][2];
#pragma unroll
      for (int ii = 0; ii < 2; ++ii) {
        int arow = wr + (ph * 2 + ii) * 16 + l15;
#pragma unroll
        for (int ks = 0; ks < 2; ++ks)
          af[ii][ks] = *(const bf16x8*)(pA + arow * 128 +
                                        (((ks * 4 + quad) ^ (arow & 7)) * 16));
      }
      if (ph == 0) { ST_A(t + 1); ST_B0(t + 1); }
      else         { ST_B123(t + 2); }
      QK_BARX();
      QK_LGKM0();
      __builtin_amdgcn_s_setprio(1);
#pragma unroll
      for (int ks = 0; ks < 2; ++ks)
#pragma unroll
        for (int ii = 0; ii < 2; ++ii)
#pragma unroll
          for (int j = 0; j < 4; ++j)
            acc[ph * 2 + ii][j] = __builtin_amdgcn_mfma_f32_16x16x32_bf16(
                af[ii][ks], bfv[j][ks], acc[ph * 2 + ii][j], 0, 0, 0);
      __builtin_amdgcn_s_setprio(0);
      if (ph == 1) {
        if (t == nt - 2) asm volatile("s_waitcnt vmcnt(0)" ::: "memory");
        else             asm volatile("s_waitcnt vmcnt(3)" ::: "memory");
      }
      QK_BARX();
    }
  }
#undef PAT
#undef PBT
#undef SEGL
#undef ST_A
#undef ST_B0
#undef ST_B123
}

// ---------------------------------------------------------------------------
// Fused QKV GEMM: C[4096,6144] = Xb[4096,2048] x WtQKV[6144,2048]^T.
// Grid 768 (32 M x 24 N) = exactly 3 rounds of 256 CUs.
__global__ __launch_bounds__(512, 2) void gemm_qkv128_kernel(
    const ushort_t* __restrict__ A, const ushort_t* __restrict__ Bt,
    ushort_t* __restrict__ outQ, ushort_t* __restrict__ outK,
    ushort_t* __restrict__ Vt, const float2* __restrict__ fcs) {
  __shared__ char lds[98304];
  const int tid = (int)threadIdx.x;
  const int w = tid >> 6, lane = tid & 63, quad = lane >> 4, l15 = lane & 15;
  const int wr = (w >> 2) * 64, wc = (w & 3) * 64;

  const int wg = ((int)blockIdx.x & 7) * 96 + ((int)blockIdx.x >> 3);
  const size_t bm0 = (size_t)(wg & 31) * 128;
  const size_t bn0 = (size_t)(wg >> 5) * 256;

  f32x4 acc[4][4];
  f32x4 z4 = {0.f, 0.f, 0.f, 0.f};
#pragma unroll
  for (int i = 0; i < 4; ++i)
#pragma unroll
    for (int j = 0; j < 4; ++j) acc[i][j] = z4;

  kloop_128x256(lds, A, Bt, bm0, bn0, acc);

  const int seg = (int)(bn0 >> 11);   // 0=Q, 1=K, 2=V
  if (seg < 2) {
    ushort_t* ob = seg ? outK : outQ;
#pragma unroll
    for (int i = 0; i < 4; ++i)
#pragma unroll
      for (int r = 0; r < 4; ++r) {
        size_t m = bm0 + wr + i * 16 + quad * 4 + r;
        int s = (int)(m & 2047);
#pragma unroll
        for (int j = 0; j < 4; ++j) {
          size_t n = (bn0 + wc + j * 16 + l15) & 2047;
          float v = acc[i][j][r];
          float v2 = dpp_xor1(v);             // RoPE pair partner (col n^1)
          int fi = ((int)n & 127) >> 1;
          float2 cs = fcs[s * 64 + fi];
          v = (lane & 1) ? (v2 * cs.y + v * cs.x) : (v * cs.x - v2 * cs.y);
          ob[m * 2048 + n] = f2bf(v);
        }
      }
  } else {
    // V segment: per-wave 64(n) x 64(m) transpose patch through LDS.
    char* T = lds + w * 8192;
#pragma unroll
    for (int i = 0; i < 4; ++i)
#pragma unroll
      for (int j = 0; j < 4; ++j) {
        int nn = j * 16 + l15;
        int md0 = i * 8 + quad * 2;
        uint32 p01 = (uint32)f2bf(acc[i][j][0]) | ((uint32)f2bf(acc[i][j][1]) << 16);
        uint32 p23 = (uint32)f2bf(acc[i][j][2]) | ((uint32)f2bf(acc[i][j][3]) << 16);
        *(uint32*)(T + nn * 128 + ((md0 ^ (nn & 31)) * 4)) = p01;
        *(uint32*)(T + nn * 128 + (((md0 + 1) ^ (nn & 31)) * 4)) = p23;
      }
    const int b = (int)(bm0 >> 11);
    const int s0 = (int)(bm0 & 2047) + wr;
    const int n2 = (int)(bn0 & 2047) + wc;
#pragma unroll
    for (int it = 0; it < 32; ++it) {
      int row = it * 2 + (lane >> 5);
      int pp = lane & 31;
      uint32 dv = *(const uint32*)(T + row * 128 + pp * 4);
      int md = pp ^ (row & 31);
      int nloc = n2 + row;
      size_t bh = (size_t)b * 16 + (nloc >> 7);
      *(uint32*)(Vt + (bh * 128 + (size_t)(nloc & 127)) * 2048 + s0 + 2 * md) = dv;
    }
  }
}

// ---------------------------------------------------------------------------
// Output projection on the same K-loop: out[4096,2048] fp32 = Ob x WtO^T.
__global__ __launch_bounds__(512, 2) void gemm_wo_kernel(
    const ushort_t* __restrict__ A, const ushort_t* __restrict__ Bt,
    float* __restrict__ out) {
  __shared__ char lds[98304];
  const int tid = (int)threadIdx.x;
  const int w = tid >> 6, lane = tid & 63, quad = lane >> 4, l15 = lane & 15;
  const int wr = (w >> 2) * 64, wc = (w & 3) * 64;

  const int wg = ((int)blockIdx.x & 7) * 32 + ((int)blockIdx.x >> 3);
  const size_t bm0 = (size_t)(wg & 31) * 128;
  const size_t bn0 = (size_t)(wg >> 5) * 256;

  f32x4 acc[4][4];
  f32x4 z4 = {0.f, 0.f, 0.f, 0.f};
#pragma unroll
  for (int i = 0; i < 4; ++i)
#pragma unroll
    for (int j = 0; j < 4; ++j) acc[i][j] = z4;

  kloop_128x256(lds, A, Bt, bm0, bn0, acc);

#pragma unroll
  for (int i = 0; i < 4; ++i)
#pragma unroll
    for (int r = 0; r < 4; ++r) {
      size_t m = bm0 + wr + i * 16 + quad * 4 + r;
#pragma unroll
      for (int j = 0; j < 4; ++j) {
        size_t n = bn0 + wc + j * 16 + l15;
        out[m * 2048 + n] = acc[i][j][r];
      }
    }
}

// ---------------------------------------------------------------------------
// Flash attention, causal, + fused adapter attention.
// R8: q-tile 64, 4 waves x 16 q-rows (mt=1). Grid 1024 = (b,h) x 32 q-tiles;
// co-resident blocks (idx, +256, +512, +768) have qt2 sums == 62 (balanced).
// LDS 40KB -> 4 blocks/CU; launch_bounds(256,4) -> 16 waves/CU.
// Defer-max THR=8 skips rescale; P packed via dpp_xor1 + v_cvt_pk_bf16_f32.
__global__ __launch_bounds__(256, 4) void flash_kernel(
    const ushort_t* __restrict__ Qb, const ushort_t* __restrict__ Kb,
    const ushort_t* __restrict__ Vt, const ushort_t* __restrict__ akb,
    const ushort_t* __restrict__ avb, const float* __restrict__ gate,
    ushort_t* __restrict__ Ob) {
  __shared__ char ldsK[16384];   // 64 tok x 256B, chunk swz ^(row&15)
  __shared__ char ldsV[16384];   // 128 d x 128B, chunk swz ^(dr&7)
  __shared__ char ldsP[8192];    // loop: P 64q x 128B swz; epilogue: pa[64][40]
  const int tid = threadIdx.x;
  const int w = tid >> 6, lane = tid & 63, quad = lane >> 4, l15 = lane & 15;
  const int idx = blockIdx.x;
  const int pg = idx >> 8, c = idx & 255;
  const int u = c >> 3, vv = c & 7;
  const int uu = (pg & 2) ? ((u + 16) & 31) : u;
  const int qt2 = (pg & 1) ? (31 - uu) : uu;     // 64-row q-tile index [0,32)
  const int hb = (pg << 3) | vv;                 // [0,32)
  const int h = hb >> 1, b = hb & 1;
  const float scale = 0.08838834764831845f;      // 1/sqrt(128)

  bf16x8 ones;
#pragma unroll
  for (int j = 0; j < 8; ++j) ones[j] = (short)0x3F80;

  // Q fragments in registers: wave rows w*16..w*16+15, 4 d-steps
  bf16x8 qf[4];
  {
    size_t qrow = (size_t)qt2 * 64 + w * 16 + l15;
    const ushort_t* base = Qb + ((size_t)b * 2048 + qrow) * 2048 + h * 128 + quad * 8;
#pragma unroll
    for (int ds = 0; ds < 4; ++ds) qf[ds] = *(const bf16x8*)(base + ds * 32);
  }

  f32x4 zero4 = {0.f, 0.f, 0.f, 0.f};
  f32x4 oacc[8];
  f32x4 osum = zero4;
  float mrow[4];
#pragma unroll
  for (int n8 = 0; n8 < 8; ++n8) oacc[n8] = zero4;
#pragma unroll
  for (int r = 0; r < 4; ++r) mrow[r] = -1e30f;

  for (int kt = 0; kt <= qt2; ++kt) {
#pragma unroll
    for (int ii = 0; ii < 4; ++ii) {
      int r0 = w * 16 + ii * 4;
      int row = r0 + (lane >> 4);
      int cl = (lane & 15) ^ (row & 15);
      async16(ldsK + r0 * 256,
              Kb + ((size_t)b * 2048 + kt * 64 + row) * 2048 + h * 128 + cl * 8);
    }
#pragma unroll
    for (int ii = 0; ii < 4; ++ii) {
      int d0 = w * 32 + ii * 8;
      int dr = d0 + (lane >> 3);
      int cl = (lane & 7) ^ (dr & 7);
      async16(ldsV + d0 * 128,
              Vt + ((size_t)(b * 16 + h) * 128 + dr) * 2048 + kt * 64 + cl * 8);
    }
    __syncthreads();

    // S = Q K^T
    f32x4 sacc[4];
#pragma unroll
    for (int nt = 0; nt < 4; ++nt) sacc[nt] = zero4;
#pragma unroll
    for (int ds = 0; ds < 4; ++ds) {
      bf16x8 kf[4];
      int ch = ds * 4 + quad;
#pragma unroll
      for (int nt = 0; nt < 4; ++nt) {
        int row = nt * 16 + l15;
        kf[nt] = *(const bf16x8*)(ldsK + row * 256 + ((ch ^ (row & 15)) * 16));
      }
#pragma unroll
      for (int nt = 0; nt < 4; ++nt)
        sacc[nt] = __builtin_amdgcn_mfma_f32_16x16x32_bf16(qf[ds], kf[nt], sacc[nt], 0, 0, 0);
    }

    // online softmax (defer-max, THR=8)
    const bool domask = (kt == qt2);
    float tmax[4] = {-1e30f, -1e30f, -1e30f, -1e30f};
    const int qbr = qt2 * 64 + w * 16 + quad * 4;
#pragma unroll
    for (int nt = 0; nt < 4; ++nt) {
      int kg = kt * 64 + nt * 16 + l15;
#pragma unroll
      for (int r = 0; r < 4; ++r) {
        float s = sacc[nt][r] * scale;
        if (domask && kg > qbr + r) s = -1e30f;
        sacc[nt][r] = s;
        tmax[r] = fmaxf(tmax[r], s);
      }
    }
    float need = 0.f;
#pragma unroll
    for (int r = 0; r < 4; ++r) {
      tmax[r] = rowmax16(tmax[r]);
      need = fmaxf(need, tmax[r] - mrow[r]);
    }
    if (__any(need > 8.0f)) {
      float alpha[4];
#pragma unroll
      for (int r = 0; r < 4; ++r) {
        float mnew = fmaxf(mrow[r], tmax[r]);
        alpha[r] = __expf(mrow[r] - mnew);
        osum[r] *= alpha[r];
        mrow[r] = mnew;
      }
#pragma unroll
      for (int n8 = 0; n8 < 8; ++n8)
#pragma unroll
        for (int r = 0; r < 4; ++r) oacc[n8][r] *= alpha[r];
    }
    // P = exp(s - mrow); pack col pairs (l, l^1) via dpp + cvt_pk, even lanes
    // store dwords into swizzled ldsP.
    uint32 pk[4][4];
#pragma unroll
    for (int nt = 0; nt < 4; ++nt)
#pragma unroll
      for (int r = 0; r < 4; ++r) {
        float pv = __expf(sacc[nt][r] - mrow[r]);
        float pn = dpp_xor1(pv);
        uint32 d_;
        asm volatile("v_cvt_pk_bf16_f32 %0, %1, %2" : "=v"(d_) : "v"(pv), "v"(pn));
        pk[nt][r] = d_;
      }
    if (!(lane & 1)) {
#pragma unroll
      for (int nt = 0; nt < 4; ++nt)
#pragma unroll
        for (int r = 0; r < 4; ++r) {
          int col = nt * 16 + l15;   // even
          int prow = w * 16 + quad * 4 + r;
          *(uint32*)(ldsP + prow * 128 + (((col >> 3) ^ (prow & 7)) * 16) + (col & 7) * 2) = pk[nt][r];
        }
    }

    // O += P V ; osum += P 1
#pragma unroll
    for (int ks = 0; ks < 2; ++ks) {
      int ch = ks * 4 + quad;
      int prow = w * 16 + l15;
      bf16x8 pf = *(const bf16x8*)(ldsP + prow * 128 + ((ch ^ (prow & 7)) * 16));
      osum = __builtin_amdgcn_mfma_f32_16x16x32_bf16(pf, ones, osum, 0, 0, 0);
#pragma unroll
      for (int n8 = 0; n8 < 8; ++n8) {
        int dr = n8 * 16 + l15;
        bf16x8 vf = *(const bf16x8*)(ldsV + dr * 128 + ((ch ^ (dr & 7)) * 16));
        oacc[n8] = __builtin_amdgcn_mfma_f32_16x16x32_bf16(pf, vf, oacc[n8], 0, 0, 0);
      }
    }
    __syncthreads();
  }

  // ---------------- fused adapter epilogue ----------------
  const float g = gate[h];
  {
    int row = w * 16 + (lane >> 2);          // wave's own 16 rows
    *(uint2*)(ldsP + row * 80 + 32 + (lane & 3) * 8) = make_uint2(0, 0);
  }
  f32x4 sa = zero4;
#pragma unroll
  for (int ds = 0; ds < 4; ++ds) {
    bf16x8 kfa = *(const bf16x8*)(akb + ((size_t)h * 16 + l15) * 128 + ds * 32 + quad * 8);
    sa = __builtin_amdgcn_mfma_f32_16x16x32_bf16(qf[ds], kfa, sa, 0, 0, 0);
  }
#pragma unroll
  for (int r = 0; r < 4; ++r) {
    float s = sa[r] * scale;
    if (l15 >= 10) s = -1e30f;
    float mx = rowmax16(s);
    float e = __expf(s - mx);
    float sum = rowsum16(e);
    float pv = g * e / sum;
    int row = w * 16 + quad * 4 + r;
    *(ushort_t*)(ldsP + row * 80 + l15 * 2) = f2bf(pv);
  }
  bf16x8 paf = *(const bf16x8*)(ldsP + (w * 16 + l15) * 80 + quad * 16);

  // normalize main attention
  float rl[4];
#pragma unroll
  for (int r = 0; r < 4; ++r) rl[r] = 1.f / osum[r];
#pragma unroll
  for (int n8 = 0; n8 < 8; ++n8)
#pragma unroll
    for (int r = 0; r < 4; ++r) oacc[n8][r] *= rl[r];
  // += pa @ avb ; store bf16
#pragma unroll
  for (int n8 = 0; n8 < 8; ++n8) {
    bf16x8 avf = *(const bf16x8*)(avb + ((size_t)h * 128 + n8 * 16 + l15) * 32 + quad * 8);
    oacc[n8] = __builtin_amdgcn_mfma_f32_16x16x32_bf16(paf, avf, oacc[n8], 0, 0, 0);
  }
  size_t qb0 = (size_t)qt2 * 64 + w * 16 + quad * 4;
#pragma unroll
  for (int n8 = 0; n8 < 8; ++n8) {
    size_t col = (size_t)h * 128 + n8 * 16 + l15;
#pragma unroll
    for (int r = 0; r < 4; ++r)
      Ob[((size_t)b * 2048 + qb0 + r) * 2048 + col] = f2bf(oacc[n8][r]);
  }
}

// ---------------------------------------------------------------------------
extern "C" void kernel_launch(void* const* d_in, const int* in_sizes, int n_in,
                              void* d_out, int out_size, void* d_ws, size_t ws_size,
                              hipStream_t stream) {
  (void)in_sizes; (void)n_in; (void)out_size; (void)ws_size;
  const float* x       = (const float*)d_in[0];
  const float* wq      = (const float*)d_in[1];
  const float* wk      = (const float*)d_in[2];
  const float* wv      = (const float*)d_in[3];
  const float* wo      = (const float*)d_in[4];
  const float* adapter = (const float*)d_in[5];
  const float* gate    = (const float*)d_in[6];
  const float* fc      = (const float*)d_in[7];
  const float* fs      = (const float*)d_in[8];

  char* ws = (char*)d_ws;
  ushort_t* Xb   = (ushort_t*)(ws + 0);           // 16 MB (reused as Ob)
  ushort_t* WtQ  = (ushort_t*)(ws + 16777216);    // 8 MB x4 contiguous
  ushort_t* WtO  = (ushort_t*)(ws + 41943040);
  ushort_t* Qb   = (ushort_t*)(ws + 50331648);    // 16 MB
  ushort_t* Kb   = (ushort_t*)(ws + 67108864);    // 16 MB
  ushort_t* Vt   = (ushort_t*)(ws + 83886080);    // 16 MB
  float*    ak   = (float*)   (ws + 100663296);   // 80 KB
  float*    av   = (float*)   (ws + 100745216);   // 80 KB
  ushort_t* akb  = (ushort_t*)(ws + 100827136);   // 64 KB
  ushort_t* avb  = (ushort_t*)(ws + 100892672);   // 128 KB
  float2*   fcs  = (float2*)  (ws + 101023744);   // 1 MB
  ushort_t* Ob   = Xb;

  cast_x_kernel<<<4096, 256, 0, stream>>>(x, Xb);
  rope_pack_kernel<<<512, 256, 0, stream>>>(fc, fs, fcs);
  transpose_w_kernel<<<dim3(32, 32, 4), 256, 0, stream>>>(wq, wk, wv, wo, WtQ);
  hipMemsetAsync(ak, 0, 163840, stream);
  adapter_kv_kernel<<<dim3(8, 16, 2), 256, 0, stream>>>(adapter, wk, wv, ak, av);
  adapter_pack_kernel<<<256, 256, 0, stream>>>(ak, av, akb, avb);
  gemm_qkv128_kernel<<<dim3(768), 512, 0, stream>>>(Xb, WtQ, Qb, Kb, Vt, fcs);
  flash_kernel<<<dim3(1024), 256, 0, stream>>>(Qb, Kb, Vt, akb, avb, gate, Ob);
  gemm_wo_kernel<<<dim3(256), 512, 0, stream>>>(Ob, WtO, (float*)d_out);
}